// Round 1
// baseline (291.857 us; speedup 1.0000x reference)
//
#include <hip/hip_runtime.h>
#include <math.h>

#define NB 16
#define BQ 2048
#define NC 256

typedef unsigned long long u64;
typedef unsigned int u32;

__device__ __forceinline__ u32 ord_f32(float f) {
  u32 b = __float_as_uint(f);
  return (b & 0x80000000u) ? ~b : (b | 0x80000000u);
}

// Kernel A: per-query softmax max/argmax (classes 0..254, softmax over all 256),
// box cxcywh->xyxy * scale. One 64-lane wave per query, 4 queries per block.
// Writes UNSORTED boxes/scores/labels into their d_out regions (kernel B permutes in-place).
__global__ __launch_bounds__(256) void score_box_kernel(
    const float* __restrict__ logits,
    const float* __restrict__ pboxes,
    const int* __restrict__ tsz,
    float* __restrict__ out)
{
#pragma clang fp contract(off)
  const int lane = threadIdx.x & 63;
  const int wv = threadIdx.x >> 6;
  const int q = blockIdx.x * 4 + wv;  // 0 .. NB*BQ-1
  const float4 lv = *reinterpret_cast<const float4*>(logits + (size_t)q * NC + lane * 4);

  // wave max over all 256 logits
  float m = fmaxf(fmaxf(lv.x, lv.y), fmaxf(lv.z, lv.w));
  #pragma unroll
  for (int d = 1; d < 64; d <<= 1) m = fmaxf(m, __shfl_xor(m, d));

  float e0 = expf(lv.x - m), e1 = expf(lv.y - m), e2 = expf(lv.z - m), e3 = expf(lv.w - m);
  float s = (e0 + e1) + (e2 + e3);
  #pragma unroll
  for (int d = 1; d < 64; d <<= 1) s += __shfl_xor(s, d);

  // probabilities (match np: per-element exp/sum, then max/argmax over first 255)
  float p0 = e0 / s, p1 = e1 / s, p2 = e2 / s, p3 = e3 / s;
  if (lane == 63) p3 = -1.0f;  // exclude class 255 from max/argmax
  const int c0 = lane * 4;
  float bp = p0; int bc = c0;
  if (p1 > bp) { bp = p1; bc = c0 + 1; }
  if (p2 > bp) { bp = p2; bc = c0 + 2; }
  if (p3 > bp) { bp = p3; bc = c0 + 3; }
  #pragma unroll
  for (int d = 1; d < 64; d <<= 1) {
    float op = __shfl_xor(bp, d);
    int   oc = __shfl_xor(bc, d);
    if (op > bp || (op == bp && oc < bc)) { bp = op; bc = oc; }  // first-occurrence ties
  }

  if (lane == 0) {
    const int b = q >> 11;
    float hf = (float)tsz[b * 2 + 0];
    float wf = (float)tsz[b * 2 + 1];
    float4 pb = *reinterpret_cast<const float4*>(pboxes + (size_t)q * 4);
    float hw = 0.5f * pb.z, hh = 0.5f * pb.w;
    float4 ob;
    ob.x = (pb.x - hw) * wf;
    ob.y = (pb.y - hh) * hf;
    ob.z = (pb.x + hw) * wf;
    ob.w = (pb.y + hh) * hf;
    *reinterpret_cast<float4*>(out + (size_t)q * 4) = ob;
    out[NB * BQ * 4 + q] = bp;          // scores region
    out[NB * BQ * 5 + q] = (float)bc;   // labels region (as float)
  }
}

// Kernel B: one block per batch. Load unsorted data into LDS, bitonic sort by
// (masked_score, idx) descending, greedy NMS on offset boxes, write sorted outputs.
__global__ __launch_bounds__(256) void sort_nms_kernel(float* __restrict__ out)
{
#pragma clang fp contract(off)
  __shared__ u64 key[BQ];           // (ordered(masked score) << 32) | orig_idx
  __shared__ float4 bx[BQ];         // scaled xyxy boxes, by orig idx
  __shared__ float sc[BQ];          // raw scores, by orig idx
  __shared__ unsigned char lb[BQ];  // labels 0..254, by orig idx
  __shared__ unsigned char kp[BQ];  // keep flags, by sorted position
  __shared__ int nv_sh;

  const int b = blockIdx.x;
  const int tid = threadIdx.x;
  float* boxes_g  = out + (size_t)b * BQ * 4;
  float* scores_g = out + NB * BQ * 4 + (size_t)b * BQ;
  float* labels_g = out + NB * BQ * 5 + (size_t)b * BQ;
  float* keep_g   = out + NB * BQ * 6 + (size_t)b * BQ;

  int cnt = 0;
  for (int q = tid; q < BQ; q += 256) {
    float s = scores_g[q];
    sc[q] = s;
    lb[q] = (unsigned char)(int)labels_g[q];
    bx[q] = *reinterpret_cast<const float4*>(boxes_g + q * 4);
    bool valid = (s >= 0.05f);
    u32 k = valid ? ord_f32(s) : 0x007FFFFFu;  // ordered(-inf)
    key[q] = ((u64)k << 32) | (u32)q;
    cnt += valid ? 1 : 0;
  }
  #pragma unroll
  for (int d = 1; d < 64; d <<= 1) cnt += __shfl_xor(cnt, d);
  if (tid == 0) nv_sh = 0;
  __syncthreads();
  if ((tid & 63) == 0) atomicAdd(&nv_sh, cnt);
  __syncthreads();
  const int nv = nv_sh;

  // bitonic sort, descending on u64 key (ties in score -> larger idx first,
  // matching reversed-stable argsort)
  for (u32 k = 2; k <= BQ; k <<= 1) {
    for (u32 j = k >> 1; j > 0; j >>= 1) {
      __syncthreads();
      for (u32 t = tid; t < BQ / 2; t += 256) {
        u32 i = ((t & ~(j - 1)) << 1) | (t & (j - 1));
        u32 ixj = i | j;
        u64 a = key[i], c = key[ixj];
        bool up = ((i & k) == 0);
        if (up == (a < c)) { key[i] = c; key[ixj] = a; }
      }
    }
  }
  __syncthreads();

  for (int p = tid; p < BQ; p += 256) kp[p] = (p < nv) ? 1 : 0;

  // greedy NMS over the first nv (valid) sorted entries
  for (int i = 0; i < nv; ++i) {
    __syncthreads();  // make prior suppressions visible
    if (!kp[i]) continue;
    int oi = (int)(u32)key[i];
    int li = lb[oi];
    float lc = (float)li * 100000.0f;  // label offset (fp32, matches ref)
    float4 A = bx[oi];
    float ax1 = A.x + lc, ay1 = A.y + lc, ax2 = A.z + lc, ay2 = A.w + lc;
    float areaA = fmaxf(ax2 - ax1, 0.0f) * fmaxf(ay2 - ay1, 0.0f);
    for (int jj = i + 1 + tid; jj < nv; jj += 256) {
      if (!kp[jj]) continue;
      int oj = (int)(u32)key[jj];
      if ((int)lb[oj] != li) continue;  // cross-label IoU is exactly 0
      float4 Bb = bx[oj];
      float bx1 = Bb.x + lc, by1 = Bb.y + lc, bx2 = Bb.z + lc, by2 = Bb.w + lc;
      float areaB = fmaxf(bx2 - bx1, 0.0f) * fmaxf(by2 - by1, 0.0f);
      float ltx = fmaxf(ax1, bx1), lty = fmaxf(ay1, by1);
      float rbx = fminf(ax2, bx2), rby = fminf(ay2, by2);
      float iw = fmaxf(rbx - ltx, 0.0f), ih = fmaxf(rby - lty, 0.0f);
      float inter = iw * ih;
      float uni = (areaA + areaB) - inter;
      float iou = inter / fmaxf(uni, 1e-6f);
      if (iou > 0.7f) kp[jj] = 0;
    }
  }
  __syncthreads();

  // write sorted outputs (regions were fully staged into LDS above)
  for (int p = tid; p < BQ; p += 256) {
    int oi = (int)(u32)key[p];
    *reinterpret_cast<float4*>(boxes_g + p * 4) = bx[oi];
    scores_g[p] = sc[oi];
    labels_g[p] = (float)lb[oi];
    keep_g[p]   = kp[p] ? 1.0f : 0.0f;
  }
}

extern "C" void kernel_launch(void* const* d_in, const int* in_sizes, int n_in,
                              void* d_out, int out_size, void* d_ws, size_t ws_size,
                              hipStream_t stream) {
  const float* logits = (const float*)d_in[0];
  const float* pboxes = (const float*)d_in[1];
  const int*   tsz    = (const int*)d_in[2];
  float* out = (float*)d_out;
  score_box_kernel<<<NB * BQ / 4, 256, 0, stream>>>(logits, pboxes, tsz, out);
  sort_nms_kernel<<<NB, 256, 0, stream>>>(out);
}

// Round 2
// 75.638 us; speedup vs baseline: 3.8586x; 3.8586x over previous
//
#include <hip/hip_runtime.h>
#include <math.h>

#define NB 16
#define BQ 2048
#define NC 256
#define NL 255   // labels 0..254 (class 255 excluded)

typedef unsigned long long u64;
typedef unsigned int u32;
typedef unsigned short u16;

__device__ __forceinline__ u32 ord_f32(float f) {
  u32 b = __float_as_uint(f);
  return (b & 0x80000000u) ? ~b : (b | 0x80000000u);
}

// Kernel A: per-query softmax max/argmax (classes 0..254, softmax over all 256),
// box cxcywh->xyxy * scale. One 64-lane wave per query, 4 queries per block.
// Writes UNSORTED boxes/scores/labels into their d_out regions (kernel B permutes in-place).
__global__ __launch_bounds__(256) void score_box_kernel(
    const float* __restrict__ logits,
    const float* __restrict__ pboxes,
    const int* __restrict__ tsz,
    float* __restrict__ out)
{
#pragma clang fp contract(off)
  const int lane = threadIdx.x & 63;
  const int wv = threadIdx.x >> 6;
  const int q = blockIdx.x * 4 + wv;  // 0 .. NB*BQ-1
  const float4 lv = *reinterpret_cast<const float4*>(logits + (size_t)q * NC + lane * 4);

  // wave max over all 256 logits
  float m = fmaxf(fmaxf(lv.x, lv.y), fmaxf(lv.z, lv.w));
  #pragma unroll
  for (int d = 1; d < 64; d <<= 1) m = fmaxf(m, __shfl_xor(m, d));

  float e0 = expf(lv.x - m), e1 = expf(lv.y - m), e2 = expf(lv.z - m), e3 = expf(lv.w - m);
  float s = (e0 + e1) + (e2 + e3);
  #pragma unroll
  for (int d = 1; d < 64; d <<= 1) s += __shfl_xor(s, d);

  // probabilities (match np: per-element exp/sum, then max/argmax over first 255)
  float p0 = e0 / s, p1 = e1 / s, p2 = e2 / s, p3 = e3 / s;
  if (lane == 63) p3 = -1.0f;  // exclude class 255 from max/argmax
  const int c0 = lane * 4;
  float bp = p0; int bc = c0;
  if (p1 > bp) { bp = p1; bc = c0 + 1; }
  if (p2 > bp) { bp = p2; bc = c0 + 2; }
  if (p3 > bp) { bp = p3; bc = c0 + 3; }
  #pragma unroll
  for (int d = 1; d < 64; d <<= 1) {
    float op = __shfl_xor(bp, d);
    int   oc = __shfl_xor(bc, d);
    if (op > bp || (op == bp && oc < bc)) { bp = op; bc = oc; }  // first-occurrence ties
  }

  if (lane == 0) {
    const int b = q >> 11;
    float hf = (float)tsz[b * 2 + 0];
    float wf = (float)tsz[b * 2 + 1];
    float4 pb = *reinterpret_cast<const float4*>(pboxes + (size_t)q * 4);
    float hw = 0.5f * pb.z, hh = 0.5f * pb.w;
    float4 ob;
    ob.x = (pb.x - hw) * wf;
    ob.y = (pb.y - hh) * hf;
    ob.z = (pb.x + hw) * wf;
    ob.w = (pb.y + hh) * hf;
    *reinterpret_cast<float4*>(out + (size_t)q * 4) = ob;
    out[NB * BQ * 4 + q] = bp;          // scores region
    out[NB * BQ * 5 + q] = (float)bc;   // labels region (as float)
  }
}

// Kernel B: one 1024-thread block per batch. Bitonic sort by (masked_score, idx)
// descending, then per-label independent greedy NMS (cross-label IoU is exactly 0
// because label offsets are >=1e5 apart vs coords <=2.7e3 -> clipped wh == 0).
__global__ __launch_bounds__(1024) void sort_nms_kernel(float* __restrict__ out)
{
#pragma clang fp contract(off)
  __shared__ u64 key[BQ];            // (ordered(masked score) << 32) | orig_idx
  __shared__ float4 bx[BQ];          // scaled xyxy boxes, by orig idx
  __shared__ float sc[BQ];           // raw scores, by orig idx
  __shared__ unsigned char lb[BQ];   // labels 0..254, by orig idx
  __shared__ unsigned char slab[BQ]; // label by sorted position (valid region)
  __shared__ unsigned char kp[BQ];   // keep flags, by sorted position
  __shared__ u16 gpos[BQ];           // sorted positions grouped by label
  __shared__ int cnt_[NL + 1];       // per-label valid count
  __shared__ int off_[NL + 1];       // per-label exclusive prefix
  __shared__ int nv_sh;

  const int b = blockIdx.x;
  const int tid = threadIdx.x;
  float* boxes_g  = out + (size_t)b * BQ * 4;
  float* scores_g = out + NB * BQ * 4 + (size_t)b * BQ;
  float* labels_g = out + NB * BQ * 5 + (size_t)b * BQ;
  float* keep_g   = out + NB * BQ * 6 + (size_t)b * BQ;

  if (tid == 0) nv_sh = 0;
  if (tid <= NL) cnt_[tid] = 0;

  int cnt = 0;
  for (int q = tid; q < BQ; q += 1024) {
    float s = scores_g[q];
    sc[q] = s;
    lb[q] = (unsigned char)(int)labels_g[q];
    bx[q] = *reinterpret_cast<const float4*>(boxes_g + q * 4);
    bool valid = (s >= 0.05f);
    u32 k = valid ? ord_f32(s) : 0x007FFFFFu;  // ordered(-inf)
    key[q] = ((u64)k << 32) | (u32)q;
    cnt += valid ? 1 : 0;
  }
  #pragma unroll
  for (int d = 1; d < 64; d <<= 1) cnt += __shfl_xor(cnt, d);
  __syncthreads();
  if ((tid & 63) == 0 && cnt) atomicAdd(&nv_sh, cnt);

  // bitonic sort, descending on u64 key (ties in score -> larger idx first,
  // matching reversed-stable argsort). 1024 threads -> 1 CE per thread/phase.
  for (u32 k = 2; k <= BQ; k <<= 1) {
    for (u32 j = k >> 1; j > 0; j >>= 1) {
      __syncthreads();
      u32 i = ((tid & ~(j - 1)) << 1) | (tid & (j - 1));
      u32 ixj = i | j;
      u64 a = key[i], c = key[ixj];
      bool up = ((i & k) == 0);
      if (up == (a < c)) { key[i] = c; key[ixj] = a; }
    }
  }
  __syncthreads();
  const int nv = nv_sh;

  // label-by-sorted-position, default keep flags, per-label counts
  for (int p = tid; p < BQ; p += 1024) {
    kp[p] = 0;
    if (p < nv) {
      int oi = (int)(u32)key[p];
      int l = lb[oi];
      slab[p] = (unsigned char)l;
      atomicAdd(&cnt_[l], 1);
    }
  }
  __syncthreads();
  if (tid == 0) {
    int run = 0;
    for (int l = 0; l < NL; ++l) { off_[l] = run; run += cnt_[l]; }
  }
  __syncthreads();

  // Thread l owns label l: gather its sorted positions in order, then run the
  // serial greedy chain thread-locally (no barriers; state is label-private).
  if (tid < NL) {
    const int l = tid;
    int w = off_[l];
    const int st = w;
    for (int p = 0; p < nv; ++p)
      if (slab[p] == (unsigned char)l) gpos[w++] = (u16)p;
    const int en = w;
    const float lc = (float)l * 100000.0f;  // label offset (fp32, matches ref)
    for (int a = st; a < en; ++a) {
      int p = gpos[a];
      int oi = (int)(u32)key[p];
      float4 A = bx[oi];
      float ax1 = A.x + lc, ay1 = A.y + lc, ax2 = A.z + lc, ay2 = A.w + lc;
      float areaA = fmaxf(ax2 - ax1, 0.0f) * fmaxf(ay2 - ay1, 0.0f);
      int keep = 1;
      for (int bb = st; bb < a; ++bb) {
        int q2 = gpos[bb];
        if (!kp[q2]) continue;
        int oj = (int)(u32)key[q2];
        float4 Bb = bx[oj];
        float bx1 = Bb.x + lc, by1 = Bb.y + lc, bx2 = Bb.z + lc, by2 = Bb.w + lc;
        float areaB = fmaxf(bx2 - bx1, 0.0f) * fmaxf(by2 - by1, 0.0f);
        float ltx = fmaxf(ax1, bx1), lty = fmaxf(ay1, by1);
        float rbx = fminf(ax2, bx2), rby = fminf(ay2, by2);
        float iw = fmaxf(rbx - ltx, 0.0f), ih = fmaxf(rby - lty, 0.0f);
        float inter = iw * ih;
        float uni = (areaB + areaA) - inter;
        // note: reference computes area[:,None]+area[None,:] i.e. A-first:
        uni = (areaA + areaB) - inter;
        float iou = inter / fmaxf(uni, 1e-6f);
        if (iou > 0.7f) { keep = 0; break; }
      }
      kp[p] = (unsigned char)keep;
    }
  }
  __syncthreads();

  // write sorted outputs
  for (int p = tid; p < BQ; p += 1024) {
    int oi = (int)(u32)key[p];
    *reinterpret_cast<float4*>(boxes_g + p * 4) = bx[oi];
    scores_g[p] = sc[oi];
    labels_g[p] = (float)lb[oi];
    keep_g[p]   = kp[p] ? 1.0f : 0.0f;
  }
}

extern "C" void kernel_launch(void* const* d_in, const int* in_sizes, int n_in,
                              void* d_out, int out_size, void* d_ws, size_t ws_size,
                              hipStream_t stream) {
  const float* logits = (const float*)d_in[0];
  const float* pboxes = (const float*)d_in[1];
  const int*   tsz    = (const int*)d_in[2];
  float* out = (float*)d_out;
  score_box_kernel<<<NB * BQ / 4, 256, 0, stream>>>(logits, pboxes, tsz, out);
  sort_nms_kernel<<<NB, 1024, 0, stream>>>(out);
}

// Round 3
// 49.995 us; speedup vs baseline: 5.8378x; 1.5129x over previous
//
#include <hip/hip_runtime.h>
#include <math.h>

#define NB 16
#define BQ 2048
#define NC 256
#define NL 255   // labels 0..254 (class 255 excluded)

typedef unsigned long long u64;
typedef unsigned int u32;
typedef unsigned short u16;
typedef unsigned char u8;

__device__ __forceinline__ u32 ord_f32(float f) {
  u32 b = __float_as_uint(f);
  return (b & 0x80000000u) ? ~b : (b | 0x80000000u);
}

__device__ __forceinline__ u64 shfl_xor_u64(u64 v, int m) {
  int lo = __shfl_xor((int)(u32)v, m, 64);
  int hi = __shfl_xor((int)(u32)(v >> 32), m, 64);
  return ((u64)(u32)hi << 32) | (u32)lo;
}

// Kernel A: per-query softmax max/argmax (classes 0..254, softmax over all 256),
// box cxcywh->xyxy * scale. One 64-lane wave per query.
__global__ __launch_bounds__(256) void score_box_kernel(
    const float* __restrict__ logits,
    const float* __restrict__ pboxes,
    const int* __restrict__ tsz,
    float* __restrict__ out)
{
#pragma clang fp contract(off)
  const int lane = threadIdx.x & 63;
  const int wv = threadIdx.x >> 6;
  const int q = blockIdx.x * 4 + wv;  // 0 .. NB*BQ-1
  const float4 lv = *reinterpret_cast<const float4*>(logits + (size_t)q * NC + lane * 4);

  float m = fmaxf(fmaxf(lv.x, lv.y), fmaxf(lv.z, lv.w));
  #pragma unroll
  for (int d = 1; d < 64; d <<= 1) m = fmaxf(m, __shfl_xor(m, d));

  float e0 = expf(lv.x - m), e1 = expf(lv.y - m), e2 = expf(lv.z - m), e3 = expf(lv.w - m);
  float s = (e0 + e1) + (e2 + e3);
  #pragma unroll
  for (int d = 1; d < 64; d <<= 1) s += __shfl_xor(s, d);

  float p0 = e0 / s, p1 = e1 / s, p2 = e2 / s, p3 = e3 / s;
  if (lane == 63) p3 = -1.0f;  // exclude class 255
  const int c0 = lane * 4;
  float bp = p0; int bc = c0;
  if (p1 > bp) { bp = p1; bc = c0 + 1; }
  if (p2 > bp) { bp = p2; bc = c0 + 2; }
  if (p3 > bp) { bp = p3; bc = c0 + 3; }
  #pragma unroll
  for (int d = 1; d < 64; d <<= 1) {
    float op = __shfl_xor(bp, d);
    int   oc = __shfl_xor(bc, d);
    if (op > bp || (op == bp && oc < bc)) { bp = op; bc = oc; }
  }

  if (lane == 0) {
    const int b = q >> 11;
    float hf = (float)tsz[b * 2 + 0];
    float wf = (float)tsz[b * 2 + 1];
    float4 pb = *reinterpret_cast<const float4*>(pboxes + (size_t)q * 4);
    float hw = 0.5f * pb.z, hh = 0.5f * pb.w;
    float4 ob;
    ob.x = (pb.x - hw) * wf;
    ob.y = (pb.y - hh) * hf;
    ob.z = (pb.x + hw) * wf;
    ob.w = (pb.y + hh) * hf;
    *reinterpret_cast<float4*>(out + (size_t)q * 4) = ob;
    out[NB * BQ * 4 + q] = bp;
    out[NB * BQ * 5 + q] = (float)bc;
  }
}

// Kernel B: one 1024-thread block per batch.
// Hybrid register/shfl/LDS bitonic sort (descending u64 key), then stable
// counting-sort-by-label group build (ballot-match ranks), per-label serial
// greedy NMS (cross-label IoU is exactly 0), writeback.
__global__ __launch_bounds__(1024) void sort_nms_kernel(float* __restrict__ out)
{
#pragma clang fp contract(off)
  __shared__ __align__(16) u64 key[BQ];  // sort staging / sorted keys
  __shared__ float4 bx[BQ];              // scaled xyxy boxes, by orig idx
  __shared__ float sc[BQ];               // raw scores, by orig idx
  __shared__ u8 lb[BQ];                  // labels, by orig idx
  __shared__ u8 kp[BQ];                  // keep flags, by sorted position
  __shared__ u16 gpos[BQ];               // sorted positions grouped by label
  __shared__ u16 hist[32 * 256];         // [chunk][label] counts -> excl prefix
  __shared__ u32 tot[256];               // per-label totals
  __shared__ u32 scn[256];               // inclusive label-count scan
  __shared__ int nv_sh;

  const int b = blockIdx.x;
  const int tid = threadIdx.x;
  const int lane = tid & 63;
  float* boxes_g  = out + (size_t)b * BQ * 4;
  float* scores_g = out + NB * BQ * 4 + (size_t)b * BQ;
  float* labels_g = out + NB * BQ * 5 + (size_t)b * BQ;
  float* keep_g   = out + NB * BQ * 6 + (size_t)b * BQ;

  if (tid == 0) nv_sh = 0;

  // ---- load: thread t owns original queries 2t, 2t+1 ----
  const int q0 = 2 * tid;
  float2 s2 = *reinterpret_cast<const float2*>(scores_g + q0);
  float2 lf = *reinterpret_cast<const float2*>(labels_g + q0);
  float4 bb0 = *reinterpret_cast<const float4*>(boxes_g + (size_t)q0 * 4);
  float4 bb1 = *reinterpret_cast<const float4*>(boxes_g + (size_t)q0 * 4 + 4);
  sc[q0] = s2.x; sc[q0 + 1] = s2.y;
  lb[q0] = (u8)(int)lf.x; lb[q0 + 1] = (u8)(int)lf.y;
  bx[q0] = bb0; bx[q0 + 1] = bb1;
  bool v0 = (s2.x >= 0.05f), v1 = (s2.y >= 0.05f);
  u64 e0 = ((u64)(v0 ? ord_f32(s2.x) : 0x007FFFFFu) << 32) | (u32)q0;
  u64 e1 = ((u64)(v1 ? ord_f32(s2.y) : 0x007FFFFFu) << 32) | (u32)(q0 + 1);
  u64 ball0 = __ballot(v0), ball1 = __ballot(v1);
  __syncthreads();
  if (lane == 0) atomicAdd(&nv_sh, (int)(__popcll(ball0) + __popcll(ball1)));

  // ---- hybrid bitonic sort, descending on u64 key ----
  // Same CE network as the verified LDS version: pair (i, i^j), direction
  // up = ((i&k)==0); j and bit0 never alias bit k, so computing up from q0
  // is exact for both slots.
  for (u32 k = 2; k <= BQ; k <<= 1) {
    for (u32 j = k >> 1; j > 0; j >>= 1) {
      const bool up = (((u32)q0 & k) == 0);
      if (j >= 128) {
        ulonglong2 w; w.x = e0; w.y = e1;
        *reinterpret_cast<ulonglong2*>(&key[q0]) = w;
        __syncthreads();
        const u32 pb = (u32)q0 ^ j;
        ulonglong2 part = *reinterpret_cast<const ulonglong2*>(&key[pb]);
        const bool keepmax = ((((u32)q0 & j) == 0) == up);
        e0 = keepmax ? (e0 > part.x ? e0 : part.x) : (e0 < part.x ? e0 : part.x);
        e1 = keepmax ? (e1 > part.y ? e1 : part.y) : (e1 < part.y ? e1 : part.y);
        __syncthreads();
      } else if (j >= 2) {
        const int j2 = (int)(j >> 1);
        const u64 y0 = shfl_xor_u64(e0, j2);
        const u64 y1 = shfl_xor_u64(e1, j2);
        const bool keepmax = (((lane & j2) == 0) == up);
        e0 = keepmax ? (e0 > y0 ? e0 : y0) : (e0 < y0 ? e0 : y0);
        e1 = keepmax ? (e1 > y1 ? e1 : y1) : (e1 < y1 ? e1 : y1);
      } else {
        const u64 mx = e0 > e1 ? e0 : e1;
        const u64 mn = e0 > e1 ? e1 : e0;
        e0 = up ? mx : mn;
        e1 = up ? mn : mx;
      }
    }
  }

  // ---- publish sorted keys; init kp, hist ----
  {
    ulonglong2 w; w.x = e0; w.y = e1;
    *reinterpret_cast<ulonglong2*>(&key[q0]) = w;
  }
  kp[tid] = 0; kp[tid + 1024] = 0;
  reinterpret_cast<u32*>(hist)[tid]        = 0;
  reinterpret_cast<u32*>(hist)[tid + 1024] = 0;
  reinterpret_cast<u32*>(hist)[tid + 2048] = 0;
  reinterpret_cast<u32*>(hist)[tid + 3072] = 0;
  __syncthreads();
  const int nv = nv_sh;

  // ---- per-chunk (64 sorted positions per wave) label ranks via ballot-match ----
  int lA, lB; u32 rA, rB;
  {
    const int p = tid;
    const u32 oi = (u32)key[p] & (BQ - 1);
    lA = (p < nv) ? (int)lb[oi] : 255;
    u64 m = ~0ull;
    #pragma unroll
    for (int bt = 0; bt < 8; ++bt) {
      const u64 vb = __ballot(((lA >> bt) & 1));
      m &= ((lA >> bt) & 1) ? vb : ~vb;
    }
    rA = (u32)__popcll(m & ((1ull << lane) - 1ull));
    if (lane == 63 - __builtin_clzll(m)) hist[(p >> 6) * 256 + lA] = (u16)__popcll(m);
  }
  {
    const int p = tid + 1024;
    const u32 oi = (u32)key[p] & (BQ - 1);
    lB = (p < nv) ? (int)lb[oi] : 255;
    u64 m = ~0ull;
    #pragma unroll
    for (int bt = 0; bt < 8; ++bt) {
      const u64 vb = __ballot(((lB >> bt) & 1));
      m &= ((lB >> bt) & 1) ? vb : ~vb;
    }
    rB = (u32)__popcll(m & ((1ull << lane) - 1ull));
    if (lane == 63 - __builtin_clzll(m)) hist[(p >> 6) * 256 + lB] = (u16)__popcll(m);
  }
  __syncthreads();

  // ---- per-label exclusive prefix over chunks (independent pipelined reads) ----
  if (tid < 256) {
    u32 run = 0;
    #pragma unroll
    for (int c = 0; c < 32; ++c) {
      const u32 v = hist[c * 256 + tid];
      hist[c * 256 + tid] = (u16)run;
      run += v;
    }
    tot[tid] = run;
  }
  __syncthreads();

  // ---- inclusive label-offset scan by wave 0 (shfl scan, no barriers) ----
  if (tid < 64) {
    u32 carry = 0;
    for (int seg = 0; seg < 4; ++seg) {
      const int l = seg * 64 + tid;
      u32 x = tot[l];
      #pragma unroll
      for (int s = 1; s < 64; s <<= 1) {
        const u32 y = __shfl_up(x, s, 64);
        if (lane >= s) x += y;
      }
      scn[l] = x + carry;
      carry += __shfl(x, 63, 64);
    }
  }
  __syncthreads();

  // ---- scatter: sorted positions grouped by label, p-ascending within label ----
  {
    const int p = tid;
    const u32 st = (lA == 0) ? 0u : scn[lA - 1];
    gpos[st + hist[(p >> 6) * 256 + lA] + rA] = (u16)p;
  }
  {
    const int p = tid + 1024;
    const u32 st = (lB == 0) ? 0u : scn[lB - 1];
    gpos[st + hist[(p >> 6) * 256 + lB] + rB] = (u16)p;
  }
  __syncthreads();

  // ---- per-label serial greedy NMS (thread l owns label l; no barriers) ----
  if (tid < NL) {
    const int l = tid;
    const int st = (l == 0) ? 0 : (int)scn[l - 1];
    const int en = (int)scn[l];
    const float lc = (float)l * 100000.0f;  // label offset (fp32, matches ref)
    for (int a = st; a < en; ++a) {
      const int p = gpos[a];
      const u32 oi = (u32)key[p] & (BQ - 1);
      const float4 A = bx[oi];
      const float ax1 = A.x + lc, ay1 = A.y + lc, ax2 = A.z + lc, ay2 = A.w + lc;
      const float areaA = fmaxf(ax2 - ax1, 0.0f) * fmaxf(ay2 - ay1, 0.0f);
      int keep = 1;
      for (int e = st; e < a; ++e) {
        const int q2 = gpos[e];
        if (!kp[q2]) continue;
        const u32 oj = (u32)key[q2] & (BQ - 1);
        const float4 Bb = bx[oj];
        const float bx1 = Bb.x + lc, by1 = Bb.y + lc, bx2 = Bb.z + lc, by2 = Bb.w + lc;
        const float areaB = fmaxf(bx2 - bx1, 0.0f) * fmaxf(by2 - by1, 0.0f);
        const float ltx = fmaxf(ax1, bx1), lty = fmaxf(ay1, by1);
        const float rbx = fminf(ax2, bx2), rby = fminf(ay2, by2);
        const float iw = fmaxf(rbx - ltx, 0.0f), ih = fmaxf(rby - lty, 0.0f);
        const float inter = iw * ih;
        const float uni = (areaA + areaB) - inter;
        const float iou = inter / fmaxf(uni, 1e-6f);
        if (iou > 0.7f) { keep = 0; break; }
      }
      kp[p] = (u8)keep;
    }
  }
  __syncthreads();

  // ---- writeback sorted outputs ----
  {
    const int p = tid;
    const u32 oi = (u32)key[p] & (BQ - 1);
    *reinterpret_cast<float4*>(boxes_g + (size_t)p * 4) = bx[oi];
    scores_g[p] = sc[oi];
    labels_g[p] = (float)lb[oi];
    keep_g[p]   = kp[p] ? 1.0f : 0.0f;
  }
  {
    const int p = tid + 1024;
    const u32 oi = (u32)key[p] & (BQ - 1);
    *reinterpret_cast<float4*>(boxes_g + (size_t)p * 4) = bx[oi];
    scores_g[p] = sc[oi];
    labels_g[p] = (float)lb[oi];
    keep_g[p]   = kp[p] ? 1.0f : 0.0f;
  }
}

extern "C" void kernel_launch(void* const* d_in, const int* in_sizes, int n_in,
                              void* d_out, int out_size, void* d_ws, size_t ws_size,
                              hipStream_t stream) {
  const float* logits = (const float*)d_in[0];
  const float* pboxes = (const float*)d_in[1];
  const int*   tsz    = (const int*)d_in[2];
  float* out = (float*)d_out;
  score_box_kernel<<<NB * BQ / 4, 256, 0, stream>>>(logits, pboxes, tsz, out);
  sort_nms_kernel<<<NB, 1024, 0, stream>>>(out);
}

// Round 4
// 40.228 us; speedup vs baseline: 7.2551x; 1.2428x over previous
//
#include <hip/hip_runtime.h>
#include <math.h>

#define NB 16
#define BQ 2048
#define NC 256
#define NL 255   // labels 0..254 (class 255 excluded)

typedef unsigned long long u64;
typedef unsigned int u32;
typedef unsigned short u16;
typedef unsigned char u8;

__device__ __forceinline__ u32 ord_f32(float f) {
  u32 b = __float_as_uint(f);
  return (b & 0x80000000u) ? ~b : (b | 0x80000000u);
}

__device__ __forceinline__ u64 shfl_xor_u64(u64 v, int m) {
  int lo = __shfl_xor((int)(u32)v, m, 64);
  int hi = __shfl_xor((int)(u32)(v >> 32), m, 64);
  return ((u64)(u32)hi << 32) | (u32)lo;
}

// Kernel A: per-query softmax max/argmax (classes 0..254, softmax over all 256),
// box cxcywh->xyxy * scale. One 64-lane wave per query. UNCHANGED (bit-exact,
// absmax=0 in rounds 1-3) — do not touch arithmetic or reduction order.
__global__ __launch_bounds__(256) void score_box_kernel(
    const float* __restrict__ logits,
    const float* __restrict__ pboxes,
    const int* __restrict__ tsz,
    float* __restrict__ out)
{
#pragma clang fp contract(off)
  const int lane = threadIdx.x & 63;
  const int wv = threadIdx.x >> 6;
  const int q = blockIdx.x * 4 + wv;  // 0 .. NB*BQ-1
  const float4 lv = *reinterpret_cast<const float4*>(logits + (size_t)q * NC + lane * 4);

  float m = fmaxf(fmaxf(lv.x, lv.y), fmaxf(lv.z, lv.w));
  #pragma unroll
  for (int d = 1; d < 64; d <<= 1) m = fmaxf(m, __shfl_xor(m, d));

  float e0 = expf(lv.x - m), e1 = expf(lv.y - m), e2 = expf(lv.z - m), e3 = expf(lv.w - m);
  float s = (e0 + e1) + (e2 + e3);
  #pragma unroll
  for (int d = 1; d < 64; d <<= 1) s += __shfl_xor(s, d);

  float p0 = e0 / s, p1 = e1 / s, p2 = e2 / s, p3 = e3 / s;
  if (lane == 63) p3 = -1.0f;  // exclude class 255
  const int c0 = lane * 4;
  float bp = p0; int bc = c0;
  if (p1 > bp) { bp = p1; bc = c0 + 1; }
  if (p2 > bp) { bp = p2; bc = c0 + 2; }
  if (p3 > bp) { bp = p3; bc = c0 + 3; }
  #pragma unroll
  for (int d = 1; d < 64; d <<= 1) {
    float op = __shfl_xor(bp, d);
    int   oc = __shfl_xor(bc, d);
    if (op > bp || (op == bp && oc < bc)) { bp = op; bc = oc; }
  }

  if (lane == 0) {
    const int b = q >> 11;
    float hf = (float)tsz[b * 2 + 0];
    float wf = (float)tsz[b * 2 + 1];
    float4 pb = *reinterpret_cast<const float4*>(pboxes + (size_t)q * 4);
    float hw = 0.5f * pb.z, hh = 0.5f * pb.w;
    float4 ob;
    ob.x = (pb.x - hw) * wf;
    ob.y = (pb.y - hh) * hf;
    ob.z = (pb.x + hw) * wf;
    ob.w = (pb.y + hh) * hf;
    *reinterpret_cast<float4*>(out + (size_t)q * 4) = ob;
    out[NB * BQ * 4 + q] = bp;
    out[NB * BQ * 5 + q] = (float)bc;
  }
}

// Kernel B: one 1024-thread block per batch.
// Valid-compaction -> bitonic sort of only the valid prefix (P=next_pow2(nv)),
// direct placement of the invalid tail (descending orig idx), counting-sort
// label groups, bitmask-parallel greedy NMS, writeback.
__global__ __launch_bounds__(1024) void sort_nms_kernel(float* __restrict__ out)
{
#pragma clang fp contract(off)
  __shared__ __align__(16) u64 key[BQ];  // sorted keys
  __shared__ float4 bx[BQ];              // scaled xyxy boxes, by orig idx
  __shared__ float sc[BQ];               // raw scores, by orig idx
  __shared__ u8 lb[BQ];                  // labels, by orig idx
  __shared__ u8 kp[BQ];                  // keep flags, by sorted position
  __shared__ u16 gpos[BQ];               // sorted positions grouped by label
  __shared__ u64 ovlg[BQ];               // suppression bitmasks, by group slot
  __shared__ u16 hist[32 * 256];         // [chunk][label] counts -> excl prefix
  __shared__ u32 tot[256];               // per-label totals
  __shared__ u32 scn[256];               // inclusive label-count scan
  __shared__ u32 wval[16], winv[16];     // per-wave valid/invalid counts

  const int b = blockIdx.x;
  const int tid = threadIdx.x;
  const int lane = tid & 63;
  const int wv = tid >> 6;
  float* boxes_g  = out + (size_t)b * BQ * 4;
  float* scores_g = out + NB * BQ * 4 + (size_t)b * BQ;
  float* labels_g = out + NB * BQ * 5 + (size_t)b * BQ;
  float* keep_g   = out + NB * BQ * 6 + (size_t)b * BQ;

  // ---- load: thread t owns original queries 2t, 2t+1 ----
  const int q0 = 2 * tid;
  float2 s2 = *reinterpret_cast<const float2*>(scores_g + q0);
  float2 lf = *reinterpret_cast<const float2*>(labels_g + q0);
  float4 bb0 = *reinterpret_cast<const float4*>(boxes_g + (size_t)q0 * 4);
  float4 bb1 = *reinterpret_cast<const float4*>(boxes_g + (size_t)q0 * 4 + 4);
  sc[q0] = s2.x; sc[q0 + 1] = s2.y;
  lb[q0] = (u8)(int)lf.x; lb[q0 + 1] = (u8)(int)lf.y;
  bx[q0] = bb0; bx[q0 + 1] = bb1;
  const bool v0 = (s2.x >= 0.05f), v1 = (s2.y >= 0.05f);
  u64 f0 = ((u64)(v0 ? ord_f32(s2.x) : 0x007FFFFFu) << 32) | (u32)q0;
  u64 f1 = ((u64)(v1 ? ord_f32(s2.y) : 0x007FFFFFu) << 32) | (u32)(q0 + 1);
  const u64 b0 = __ballot(v0), b1 = __ballot(v1);
  if (lane == 0) {
    const u32 c = (u32)(__popcll(b0) + __popcll(b1));
    wval[wv] = c;
    winv[wv] = 128u - c;
  }
  __syncthreads();

  // ---- per-thread compaction ranks ----
  int nv = 0, voff = 0, ioff = 0;
  #pragma unroll
  for (int w = 0; w < 16; ++w) {
    const int c = (int)wval[w];
    nv += c;
    if (w < wv) { voff += c; ioff += (int)winv[w]; }
  }
  const int tinv = BQ - nv;
  const u64 below = (1ull << lane) - 1ull;
  // lexicographic (wave, lane, elem) order — bijective for valids (pre-order
  // irrelevant: comparison sort follows), EXACT ascending-idx order for invalids.
  const int vr0 = voff + (int)__popcll(b0 & below) + (int)__popcll(b1 & below);
  const int ir0 = ioff + (int)__popcll(~b0 & below) + (int)__popcll(~b1 & below);
  const int vr1 = vr0 + (v0 ? 1 : 0);
  const int ir1 = ir0 + (v0 ? 0 : 1);
  // invalid tail: position nv + (tinv-1-ir) = descending original index
  const int ip0 = v0 ? vr0 : (nv + (tinv - 1 - ir0));
  const int ip1 = v1 ? vr1 : (nv + (tinv - 1 - ir1));

  // zero keys (pad entries sort to the tail of [0,P) since any valid key > 0)
  {
    ulonglong2 z; z.x = 0; z.y = 0;
    *reinterpret_cast<ulonglong2*>(&key[q0]) = z;
  }
  __syncthreads();
  if (v0) key[ip0] = f0;
  if (v1) key[ip1] = f1;
  __syncthreads();

  u32 P = 1;
  while ((int)P < nv) P <<= 1;

  // ---- hybrid bitonic sort over [0,P), descending u64 key ----
  // Threads with q0 >= P shuffle/store garbage harmlessly: their key slots lie
  // in [nv,2048) and are overwritten by the invalid placement below; active
  // partners (i^j < P) never read them.
  u64 e0 = key[q0], e1 = key[q0 + 1];
  for (u32 k = 2; k <= P; k <<= 1) {
    for (u32 j = k >> 1; j > 0; j >>= 1) {
      const bool up = (((u32)q0 & k) == 0);
      if (j >= 128) {
        ulonglong2 w2; w2.x = e0; w2.y = e1;
        *reinterpret_cast<ulonglong2*>(&key[q0]) = w2;
        __syncthreads();
        const u32 pb = (u32)q0 ^ j;
        ulonglong2 part = *reinterpret_cast<const ulonglong2*>(&key[pb]);
        const bool keepmax = ((((u32)q0 & j) == 0) == up);
        e0 = keepmax ? (e0 > part.x ? e0 : part.x) : (e0 < part.x ? e0 : part.x);
        e1 = keepmax ? (e1 > part.y ? e1 : part.y) : (e1 < part.y ? e1 : part.y);
        __syncthreads();
      } else if (j >= 2) {
        const int j2 = (int)(j >> 1);
        const u64 y0 = shfl_xor_u64(e0, j2);
        const u64 y1 = shfl_xor_u64(e1, j2);
        const bool keepmax = (((lane & j2) == 0) == up);
        e0 = keepmax ? (e0 > y0 ? e0 : y0) : (e0 < y0 ? e0 : y0);
        e1 = keepmax ? (e1 > y1 ? e1 : y1) : (e1 < y1 ? e1 : y1);
      } else {
        const u64 mx = e0 > e1 ? e0 : e1;
        const u64 mn = e0 > e1 ? e1 : e0;
        e0 = up ? mx : mn;
        e1 = up ? mn : mx;
      }
    }
  }
  {
    ulonglong2 w2; w2.x = e0; w2.y = e1;
    *reinterpret_cast<ulonglong2*>(&key[q0]) = w2;
  }
  __syncthreads();

  // ---- place invalid tail; init kp, hist ----
  if (!v0) key[ip0] = f0;
  if (!v1) key[ip1] = f1;
  kp[tid] = 0; kp[tid + 1024] = 0;
  reinterpret_cast<u32*>(hist)[tid]        = 0;
  reinterpret_cast<u32*>(hist)[tid + 1024] = 0;
  reinterpret_cast<u32*>(hist)[tid + 2048] = 0;
  reinterpret_cast<u32*>(hist)[tid + 3072] = 0;
  __syncthreads();

  // ---- per-chunk (64 sorted positions per wave) label ranks via ballot-match ----
  int lA, lB; u32 rA, rB;
  {
    const int p = tid;
    const u32 oi = (u32)key[p] & (BQ - 1);
    lA = (p < nv) ? (int)lb[oi] : 255;
    u64 m = ~0ull;
    #pragma unroll
    for (int bt = 0; bt < 8; ++bt) {
      const u64 vb = __ballot(((lA >> bt) & 1));
      m &= ((lA >> bt) & 1) ? vb : ~vb;
    }
    rA = (u32)__popcll(m & below);
    if (lane == 63 - __builtin_clzll(m)) hist[(p >> 6) * 256 + lA] = (u16)__popcll(m);
  }
  {
    const int p = tid + 1024;
    const u32 oi = (u32)key[p] & (BQ - 1);
    lB = (p < nv) ? (int)lb[oi] : 255;
    u64 m = ~0ull;
    #pragma unroll
    for (int bt = 0; bt < 8; ++bt) {
      const u64 vb = __ballot(((lB >> bt) & 1));
      m &= ((lB >> bt) & 1) ? vb : ~vb;
    }
    rB = (u32)__popcll(m & below);
    if (lane == 63 - __builtin_clzll(m)) hist[(p >> 6) * 256 + lB] = (u16)__popcll(m);
  }
  __syncthreads();

  // ---- per-label exclusive prefix over chunks ----
  if (tid < 256) {
    u32 run = 0;
    #pragma unroll
    for (int c = 0; c < 32; ++c) {
      const u32 v = hist[c * 256 + tid];
      hist[c * 256 + tid] = (u16)run;
      run += v;
    }
    tot[tid] = run;
  }
  __syncthreads();

  // ---- inclusive label-offset scan by wave 0 ----
  if (tid < 64) {
    u32 carry = 0;
    for (int seg = 0; seg < 4; ++seg) {
      const int l = seg * 64 + tid;
      u32 x = tot[l];
      #pragma unroll
      for (int s = 1; s < 64; s <<= 1) {
        const u32 y = __shfl_up(x, s, 64);
        if (lane >= s) x += y;
      }
      scn[l] = x + carry;
      carry += __shfl(x, 63, 64);
    }
  }
  __syncthreads();

  // ---- scatter: group slots by label, sorted-position-ascending within label ----
  u32 gA, gB;
  {
    const int p = tid;
    const u32 st = (lA == 0) ? 0u : scn[lA - 1];
    gA = (u32)hist[(p >> 6) * 256 + lA] + rA;
    gpos[st + gA] = (u16)p;
  }
  {
    const int p = tid + 1024;
    const u32 st = (lB == 0) ? 0u : scn[lB - 1];
    gB = (u32)hist[(p >> 6) * 256 + lB] + rB;
    gpos[st + gB] = (u16)p;
  }
  __syncthreads();

  // ---- parallel mask build: overlap bitmask vs earlier same-label members ----
  #pragma unroll
  for (int half = 0; half < 2; ++half) {
    const int p = tid + half * 1024;
    const int l = half ? lB : lA;
    const u32 g = half ? gB : gA;
    if (p < nv && g < 64) {
      const u32 st = (l == 0) ? 0u : scn[l - 1];
      const u32 oi = (u32)key[p] & (BQ - 1);
      const float4 A = bx[oi];
      const float lc = (float)l * 100000.0f;
      const float ax1 = A.x + lc, ay1 = A.y + lc, ax2 = A.z + lc, ay2 = A.w + lc;
      const float areaA = fmaxf(ax2 - ax1, 0.0f) * fmaxf(ay2 - ay1, 0.0f);
      u64 m = 0;
      for (u32 r = 0; r < g; ++r) {
        const int p2 = gpos[st + r];
        const u32 oj = (u32)key[p2] & (BQ - 1);
        const float4 Bb = bx[oj];
        const float bx1 = Bb.x + lc, by1 = Bb.y + lc, bx2 = Bb.z + lc, by2 = Bb.w + lc;
        const float areaB = fmaxf(bx2 - bx1, 0.0f) * fmaxf(by2 - by1, 0.0f);
        const float ltx = fmaxf(ax1, bx1), lty = fmaxf(ay1, by1);
        const float rbx = fminf(ax2, bx2), rby = fminf(ay2, by2);
        const float iw = fmaxf(rbx - ltx, 0.0f), ih = fmaxf(rby - lty, 0.0f);
        const float inter = iw * ih;
        const float uni = (areaA + areaB) - inter;
        const float iou = inter / fmaxf(uni, 1e-6f);
        if (iou > 0.7f) m |= (1ull << r);
      }
      ovlg[st + g] = m;
    }
  }
  __syncthreads();

  // ---- per-label greedy resolution (register bitops; serial fallback k>64) ----
  if (tid < NL) {
    const int l = tid;
    const int st = (l == 0) ? 0 : (int)scn[l - 1];
    const int en = (int)scn[l];
    const int k = en - st;
    if (k <= 64) {
      u64 kept = 0;
      for (int r = 0; r < k; ++r) {
        const u64 m = ovlg[st + r];
        const int keep = ((m & kept) == 0) ? 1 : 0;
        kept |= (u64)keep << r;
        kp[gpos[st + r]] = (u8)keep;
      }
    } else {
      const float lc = (float)l * 100000.0f;
      for (int a = st; a < en; ++a) {
        const int p = gpos[a];
        const u32 oi = (u32)key[p] & (BQ - 1);
        const float4 A = bx[oi];
        const float ax1 = A.x + lc, ay1 = A.y + lc, ax2 = A.z + lc, ay2 = A.w + lc;
        const float areaA = fmaxf(ax2 - ax1, 0.0f) * fmaxf(ay2 - ay1, 0.0f);
        int keep = 1;
        for (int e = st; e < a; ++e) {
          const int q2 = gpos[e];
          if (!kp[q2]) continue;
          const u32 oj = (u32)key[q2] & (BQ - 1);
          const float4 Bb = bx[oj];
          const float bx1 = Bb.x + lc, by1 = Bb.y + lc, bx2 = Bb.z + lc, by2 = Bb.w + lc;
          const float areaB = fmaxf(bx2 - bx1, 0.0f) * fmaxf(by2 - by1, 0.0f);
          const float ltx = fmaxf(ax1, bx1), lty = fmaxf(ay1, by1);
          const float rbx = fminf(ax2, bx2), rby = fminf(ay2, by2);
          const float iw = fmaxf(rbx - ltx, 0.0f), ih = fmaxf(rby - lty, 0.0f);
          const float inter = iw * ih;
          const float uni = (areaA + areaB) - inter;
          const float iou = inter / fmaxf(uni, 1e-6f);
          if (iou > 0.7f) { keep = 0; break; }
        }
        kp[p] = (u8)keep;
      }
    }
  }
  __syncthreads();

  // ---- writeback sorted outputs ----
  {
    const int p = tid;
    const u32 oi = (u32)key[p] & (BQ - 1);
    *reinterpret_cast<float4*>(boxes_g + (size_t)p * 4) = bx[oi];
    scores_g[p] = sc[oi];
    labels_g[p] = (float)lb[oi];
    keep_g[p]   = kp[p] ? 1.0f : 0.0f;
  }
  {
    const int p = tid + 1024;
    const u32 oi = (u32)key[p] & (BQ - 1);
    *reinterpret_cast<float4*>(boxes_g + (size_t)p * 4) = bx[oi];
    scores_g[p] = sc[oi];
    labels_g[p] = (float)lb[oi];
    keep_g[p]   = kp[p] ? 1.0f : 0.0f;
  }
}

extern "C" void kernel_launch(void* const* d_in, const int* in_sizes, int n_in,
                              void* d_out, int out_size, void* d_ws, size_t ws_size,
                              hipStream_t stream) {
  const float* logits = (const float*)d_in[0];
  const float* pboxes = (const float*)d_in[1];
  const int*   tsz    = (const int*)d_in[2];
  float* out = (float*)d_out;
  score_box_kernel<<<NB * BQ / 4, 256, 0, stream>>>(logits, pboxes, tsz, out);
  sort_nms_kernel<<<NB, 1024, 0, stream>>>(out);
}

// Round 5
// 33.569 us; speedup vs baseline: 8.6942x; 1.1983x over previous
//
#include <hip/hip_runtime.h>
#include <math.h>

#define NB 16
#define BQ 2048
#define NC 256
#define NL 255   // labels 0..254 (class 255 excluded)

typedef unsigned long long u64;
typedef unsigned int u32;
typedef unsigned short u16;
typedef unsigned char u8;

__device__ __forceinline__ u32 ord_f32(float f) {
  u32 b = __float_as_uint(f);
  return (b & 0x80000000u) ? ~b : (b | 0x80000000u);
}

__device__ __forceinline__ u64 shfl_xor_u64(u64 v, int m) {
  int lo = __shfl_xor((int)(u32)v, m, 64);
  int hi = __shfl_xor((int)(u32)(v >> 32), m, 64);
  return ((u64)(u32)hi << 32) | (u32)lo;
}

// Kernel A: 16 lanes per query (4 queries per wave). Lane g owns the 16
// CONSECUTIVE classes [16g, 16g+15]; the per-lane balanced tree + 4 xor-phases
// reproduce the EXACT summation DAG (balanced binary tree over 256 leaves in
// index order) of the proven absmax=0 one-wave-per-query version. fmax is
// order-insensitive; argmax keeps first-occurrence semantics on probs.
__global__ __launch_bounds__(256) void score_box_kernel(
    const float* __restrict__ logits,
    const float* __restrict__ pboxes,
    const int* __restrict__ tsz,
    float* __restrict__ out)
{
#pragma clang fp contract(off)
  const int lane = threadIdx.x & 63;
  const int g = lane & 15;            // sub-lane within the 16-lane group
  const int wv = threadIdx.x >> 6;
  const int q = (blockIdx.x * 4 + wv) * 4 + (lane >> 4);  // 16 queries/block
  const float* row = logits + (size_t)q * NC + g * 16;
  const float4 la = *reinterpret_cast<const float4*>(row);
  const float4 lb4 = *reinterpret_cast<const float4*>(row + 4);
  const float4 lc = *reinterpret_cast<const float4*>(row + 8);
  const float4 ld = *reinterpret_cast<const float4*>(row + 12);

  // max over all 256 logits (order-insensitive)
  float m = fmaxf(fmaxf(fmaxf(la.x, la.y), fmaxf(la.z, la.w)),
           fmaxf(fmaxf(fmaxf(lb4.x, lb4.y), fmaxf(lb4.z, lb4.w)),
           fmaxf(fmaxf(fmaxf(lc.x, lc.y), fmaxf(lc.z, lc.w)),
                 fmaxf(fmaxf(ld.x, ld.y), fmaxf(ld.z, ld.w)))));
  #pragma unroll
  for (int d = 1; d < 16; d <<= 1) m = fmaxf(m, __shfl_xor(m, d));

  float4 ea, eb, ec, ed;
  ea.x = expf(la.x - m);  ea.y = expf(la.y - m);  ea.z = expf(la.z - m);  ea.w = expf(la.w - m);
  eb.x = expf(lb4.x - m); eb.y = expf(lb4.y - m); eb.z = expf(lb4.z - m); eb.w = expf(lb4.w - m);
  ec.x = expf(lc.x - m);  ec.y = expf(lc.y - m);  ec.z = expf(lc.z - m);  ec.w = expf(lc.w - m);
  ed.x = expf(ld.x - m);  ed.y = expf(ld.y - m);  ed.z = expf(ld.z - m);  ed.w = expf(ld.w - m);

  // balanced binary tree over the 16 consecutive classes, in index order
  float s = (((ea.x + ea.y) + (ea.z + ea.w)) + ((eb.x + eb.y) + (eb.z + eb.w)))
          + (((ec.x + ec.y) + (ec.z + ec.w)) + ((ed.x + ed.y) + (ed.z + ed.w)));
  #pragma unroll
  for (int d = 1; d < 16; d <<= 1) s += __shfl_xor(s, d);

  // per-lane argmax over probs e/s (first occurrence on ties); class 255 excluded
  const int c0 = g * 16;
  float bp = ea.x / s; int bc = c0;
  float p;
  p = ea.y / s; if (p > bp) { bp = p; bc = c0 + 1; }
  p = ea.z / s; if (p > bp) { bp = p; bc = c0 + 2; }
  p = ea.w / s; if (p > bp) { bp = p; bc = c0 + 3; }
  p = eb.x / s; if (p > bp) { bp = p; bc = c0 + 4; }
  p = eb.y / s; if (p > bp) { bp = p; bc = c0 + 5; }
  p = eb.z / s; if (p > bp) { bp = p; bc = c0 + 6; }
  p = eb.w / s; if (p > bp) { bp = p; bc = c0 + 7; }
  p = ec.x / s; if (p > bp) { bp = p; bc = c0 + 8; }
  p = ec.y / s; if (p > bp) { bp = p; bc = c0 + 9; }
  p = ec.z / s; if (p > bp) { bp = p; bc = c0 + 10; }
  p = ec.w / s; if (p > bp) { bp = p; bc = c0 + 11; }
  p = ed.x / s; if (p > bp) { bp = p; bc = c0 + 12; }
  p = ed.y / s; if (p > bp) { bp = p; bc = c0 + 13; }
  p = ed.z / s; if (p > bp) { bp = p; bc = c0 + 14; }
  p = ed.w / s; if (g != 15 && p > bp) { bp = p; bc = c0 + 15; }  // skip class 255
  #pragma unroll
  for (int d = 1; d < 16; d <<= 1) {
    const float op = __shfl_xor(bp, d);
    const int   oc = __shfl_xor(bc, d);
    if (op > bp || (op == bp && oc < bc)) { bp = op; bc = oc; }
  }

  if (g == 0) {
    const int b = q >> 11;
    float hf = (float)tsz[b * 2 + 0];
    float wf = (float)tsz[b * 2 + 1];
    float4 pb = *reinterpret_cast<const float4*>(pboxes + (size_t)q * 4);
    float hw = 0.5f * pb.z, hh = 0.5f * pb.w;
    float4 ob;
    ob.x = (pb.x - hw) * wf;
    ob.y = (pb.y - hh) * hf;
    ob.z = (pb.x + hw) * wf;
    ob.w = (pb.y + hh) * hf;
    *reinterpret_cast<float4*>(out + (size_t)q * 4) = ob;
    out[NB * BQ * 4 + q] = bp;
    out[NB * BQ * 5 + q] = (float)bc;
  }
}

// Kernel B: one 1024-thread block per batch.
// Valid-compaction -> bitonic sort of only the valid prefix (P=next_pow2(nv)),
// direct placement of the invalid tail (descending orig idx), counting-sort
// label groups, bitmask-parallel greedy NMS, writeback.
__global__ __launch_bounds__(1024) void sort_nms_kernel(float* __restrict__ out)
{
#pragma clang fp contract(off)
  __shared__ __align__(16) u64 key[BQ];  // sorted keys
  __shared__ float4 bx[BQ];              // scaled xyxy boxes, by orig idx
  __shared__ float sc[BQ];               // raw scores, by orig idx
  __shared__ u8 lb[BQ];                  // labels, by orig idx
  __shared__ u8 kp[BQ];                  // keep flags, by sorted position
  __shared__ u16 gpos[BQ];               // sorted positions grouped by label
  __shared__ u64 ovlg[BQ];               // suppression bitmasks, by group slot
  __shared__ u16 hist[32 * 256];         // [chunk][label] counts -> excl prefix
  __shared__ u32 tot[256];               // per-label totals
  __shared__ u32 scn[256];               // inclusive label-count scan
  __shared__ u32 wval[16], winv[16];     // per-wave valid/invalid counts

  const int b = blockIdx.x;
  const int tid = threadIdx.x;
  const int lane = tid & 63;
  const int wv = tid >> 6;
  float* boxes_g  = out + (size_t)b * BQ * 4;
  float* scores_g = out + NB * BQ * 4 + (size_t)b * BQ;
  float* labels_g = out + NB * BQ * 5 + (size_t)b * BQ;
  float* keep_g   = out + NB * BQ * 6 + (size_t)b * BQ;

  // ---- load: thread t owns original queries 2t, 2t+1 ----
  const int q0 = 2 * tid;
  float2 s2 = *reinterpret_cast<const float2*>(scores_g + q0);
  float2 lf = *reinterpret_cast<const float2*>(labels_g + q0);
  float4 bb0 = *reinterpret_cast<const float4*>(boxes_g + (size_t)q0 * 4);
  float4 bb1 = *reinterpret_cast<const float4*>(boxes_g + (size_t)q0 * 4 + 4);
  sc[q0] = s2.x; sc[q0 + 1] = s2.y;
  lb[q0] = (u8)(int)lf.x; lb[q0 + 1] = (u8)(int)lf.y;
  bx[q0] = bb0; bx[q0 + 1] = bb1;
  const bool v0 = (s2.x >= 0.05f), v1 = (s2.y >= 0.05f);
  u64 f0 = ((u64)(v0 ? ord_f32(s2.x) : 0x007FFFFFu) << 32) | (u32)q0;
  u64 f1 = ((u64)(v1 ? ord_f32(s2.y) : 0x007FFFFFu) << 32) | (u32)(q0 + 1);
  const u64 b0 = __ballot(v0), b1 = __ballot(v1);
  if (lane == 0) {
    const u32 c = (u32)(__popcll(b0) + __popcll(b1));
    wval[wv] = c;
    winv[wv] = 128u - c;
  }
  __syncthreads();

  // ---- per-thread compaction ranks ----
  int nv = 0, voff = 0, ioff = 0;
  #pragma unroll
  for (int w = 0; w < 16; ++w) {
    const int c = (int)wval[w];
    nv += c;
    if (w < wv) { voff += c; ioff += (int)winv[w]; }
  }
  const int tinv = BQ - nv;
  const u64 below = (1ull << lane) - 1ull;
  const int vr0 = voff + (int)__popcll(b0 & below) + (int)__popcll(b1 & below);
  const int ir0 = ioff + (int)__popcll(~b0 & below) + (int)__popcll(~b1 & below);
  const int vr1 = vr0 + (v0 ? 1 : 0);
  const int ir1 = ir0 + (v0 ? 0 : 1);
  // invalid tail: position nv + (tinv-1-ir) = descending original index
  const int ip0 = v0 ? vr0 : (nv + (tinv - 1 - ir0));
  const int ip1 = v1 ? vr1 : (nv + (tinv - 1 - ir1));

  // zero keys (pad entries sort to the tail of [0,P) since any valid key > 0)
  {
    ulonglong2 z; z.x = 0; z.y = 0;
    *reinterpret_cast<ulonglong2*>(&key[q0]) = z;
  }
  __syncthreads();
  if (v0) key[ip0] = f0;
  if (v1) key[ip1] = f1;
  __syncthreads();

  u32 P = 1;
  while ((int)P < nv) P <<= 1;
  // wave-uniform activity gate: this wave's 128 slots start at (q0 & ~127);
  // waves whose slots all lie >= P skip sort compute (their slots are
  // overwritten by the invalid-tail placement; active partners stay < P).
  const bool wactive = ((u32)(q0 & ~127) < P);

  // ---- hybrid bitonic sort over [0,P), descending u64 key ----
  u64 e0 = key[q0], e1 = key[q0 + 1];
  for (u32 k = 2; k <= P; k <<= 1) {
    for (u32 j = k >> 1; j > 0; j >>= 1) {
      const bool up = (((u32)q0 & k) == 0);
      if (j >= 128) {
        if (wactive) {
          ulonglong2 w2; w2.x = e0; w2.y = e1;
          *reinterpret_cast<ulonglong2*>(&key[q0]) = w2;
        }
        __syncthreads();
        if (wactive) {
          const u32 pb = (u32)q0 ^ j;
          ulonglong2 part = *reinterpret_cast<const ulonglong2*>(&key[pb]);
          const bool keepmax = ((((u32)q0 & j) == 0) == up);
          e0 = keepmax ? (e0 > part.x ? e0 : part.x) : (e0 < part.x ? e0 : part.x);
          e1 = keepmax ? (e1 > part.y ? e1 : part.y) : (e1 < part.y ? e1 : part.y);
        }
        __syncthreads();
      } else if (wactive) {
        if (j >= 2) {
          const int j2 = (int)(j >> 1);
          const u64 y0 = shfl_xor_u64(e0, j2);
          const u64 y1 = shfl_xor_u64(e1, j2);
          const bool keepmax = (((lane & j2) == 0) == up);
          e0 = keepmax ? (e0 > y0 ? e0 : y0) : (e0 < y0 ? e0 : y0);
          e1 = keepmax ? (e1 > y1 ? e1 : y1) : (e1 < y1 ? e1 : y1);
        } else {
          const u64 mx = e0 > e1 ? e0 : e1;
          const u64 mn = e0 > e1 ? e1 : e0;
          e0 = up ? mx : mn;
          e1 = up ? mn : mx;
        }
      }
    }
  }
  if (wactive) {
    ulonglong2 w2; w2.x = e0; w2.y = e1;
    *reinterpret_cast<ulonglong2*>(&key[q0]) = w2;
  }
  __syncthreads();

  // ---- place invalid tail; init kp, hist ----
  if (!v0) key[ip0] = f0;
  if (!v1) key[ip1] = f1;
  kp[tid] = 0; kp[tid + 1024] = 0;
  reinterpret_cast<u32*>(hist)[tid]        = 0;
  reinterpret_cast<u32*>(hist)[tid + 1024] = 0;
  reinterpret_cast<u32*>(hist)[tid + 2048] = 0;
  reinterpret_cast<u32*>(hist)[tid + 3072] = 0;
  __syncthreads();

  // ---- per-chunk (64 sorted positions per wave) label ranks via ballot-match ----
  int lA, lB; u32 rA, rB;
  {
    const int p = tid;
    const u32 oi = (u32)key[p] & (BQ - 1);
    lA = (p < nv) ? (int)lb[oi] : 255;
    u64 m = ~0ull;
    #pragma unroll
    for (int bt = 0; bt < 8; ++bt) {
      const u64 vb = __ballot(((lA >> bt) & 1));
      m &= ((lA >> bt) & 1) ? vb : ~vb;
    }
    rA = (u32)__popcll(m & below);
    if (lane == 63 - __builtin_clzll(m)) hist[(p >> 6) * 256 + lA] = (u16)__popcll(m);
  }
  {
    const int p = tid + 1024;
    const u32 oi = (u32)key[p] & (BQ - 1);
    lB = (p < nv) ? (int)lb[oi] : 255;
    u64 m = ~0ull;
    #pragma unroll
    for (int bt = 0; bt < 8; ++bt) {
      const u64 vb = __ballot(((lB >> bt) & 1));
      m &= ((lB >> bt) & 1) ? vb : ~vb;
    }
    rB = (u32)__popcll(m & below);
    if (lane == 63 - __builtin_clzll(m)) hist[(p >> 6) * 256 + lB] = (u16)__popcll(m);
  }
  __syncthreads();

  // ---- per-label exclusive prefix over chunks ----
  if (tid < 256) {
    u32 run = 0;
    #pragma unroll
    for (int c = 0; c < 32; ++c) {
      const u32 v = hist[c * 256 + tid];
      hist[c * 256 + tid] = (u16)run;
      run += v;
    }
    tot[tid] = run;
  }
  __syncthreads();

  // ---- inclusive label-offset scan by wave 0 ----
  if (tid < 64) {
    u32 carry = 0;
    for (int seg = 0; seg < 4; ++seg) {
      const int l = seg * 64 + tid;
      u32 x = tot[l];
      #pragma unroll
      for (int s = 1; s < 64; s <<= 1) {
        const u32 y = __shfl_up(x, s, 64);
        if (lane >= s) x += y;
      }
      scn[l] = x + carry;
      carry += __shfl(x, 63, 64);
    }
  }
  __syncthreads();

  // ---- scatter: group slots by label, sorted-position-ascending within label ----
  u32 gA, gB;
  {
    const int p = tid;
    const u32 st = (lA == 0) ? 0u : scn[lA - 1];
    gA = (u32)hist[(p >> 6) * 256 + lA] + rA;
    gpos[st + gA] = (u16)p;
  }
  {
    const int p = tid + 1024;
    const u32 st = (lB == 0) ? 0u : scn[lB - 1];
    gB = (u32)hist[(p >> 6) * 256 + lB] + rB;
    gpos[st + gB] = (u16)p;
  }
  __syncthreads();

  // ---- parallel mask build: overlap bitmask vs earlier same-label members ----
  #pragma unroll
  for (int half = 0; half < 2; ++half) {
    const int p = tid + half * 1024;
    const int l = half ? lB : lA;
    const u32 g = half ? gB : gA;
    if (p < nv && g < 64) {
      const u32 st = (l == 0) ? 0u : scn[l - 1];
      const u32 oi = (u32)key[p] & (BQ - 1);
      const float4 A = bx[oi];
      const float lc = (float)l * 100000.0f;
      const float ax1 = A.x + lc, ay1 = A.y + lc, ax2 = A.z + lc, ay2 = A.w + lc;
      const float areaA = fmaxf(ax2 - ax1, 0.0f) * fmaxf(ay2 - ay1, 0.0f);
      u64 m = 0;
      for (u32 r = 0; r < g; ++r) {
        const int p2 = gpos[st + r];
        const u32 oj = (u32)key[p2] & (BQ - 1);
        const float4 Bb = bx[oj];
        const float bx1 = Bb.x + lc, by1 = Bb.y + lc, bx2 = Bb.z + lc, by2 = Bb.w + lc;
        const float areaB = fmaxf(bx2 - bx1, 0.0f) * fmaxf(by2 - by1, 0.0f);
        const float ltx = fmaxf(ax1, bx1), lty = fmaxf(ay1, by1);
        const float rbx = fminf(ax2, bx2), rby = fminf(ay2, by2);
        const float iw = fmaxf(rbx - ltx, 0.0f), ih = fmaxf(rby - lty, 0.0f);
        const float inter = iw * ih;
        const float uni = (areaA + areaB) - inter;
        const float iou = inter / fmaxf(uni, 1e-6f);
        if (iou > 0.7f) m |= (1ull << r);
      }
      ovlg[st + g] = m;
    }
  }
  __syncthreads();

  // ---- per-label greedy resolution (register bitops; serial fallback k>64) ----
  if (tid < NL) {
    const int l = tid;
    const int st = (l == 0) ? 0 : (int)scn[l - 1];
    const int en = (int)scn[l];
    const int k = en - st;
    if (k <= 64) {
      u64 kept = 0;
      for (int r = 0; r < k; ++r) {
        const u64 m = ovlg[st + r];
        const int keep = ((m & kept) == 0) ? 1 : 0;
        kept |= (u64)keep << r;
        kp[gpos[st + r]] = (u8)keep;
      }
    } else {
      const float lc = (float)l * 100000.0f;
      for (int a = st; a < en; ++a) {
        const int p = gpos[a];
        const u32 oi = (u32)key[p] & (BQ - 1);
        const float4 A = bx[oi];
        const float ax1 = A.x + lc, ay1 = A.y + lc, ax2 = A.z + lc, ay2 = A.w + lc;
        const float areaA = fmaxf(ax2 - ax1, 0.0f) * fmaxf(ay2 - ay1, 0.0f);
        int keep = 1;
        for (int e = st; e < a; ++e) {
          const int q2 = gpos[e];
          if (!kp[q2]) continue;
          const u32 oj = (u32)key[q2] & (BQ - 1);
          const float4 Bb = bx[oj];
          const float bx1 = Bb.x + lc, by1 = Bb.y + lc, bx2 = Bb.z + lc, by2 = Bb.w + lc;
          const float areaB = fmaxf(bx2 - bx1, 0.0f) * fmaxf(by2 - by1, 0.0f);
          const float ltx = fmaxf(ax1, bx1), lty = fmaxf(ay1, by1);
          const float rbx = fminf(ax2, bx2), rby = fminf(ay2, by2);
          const float iw = fmaxf(rbx - ltx, 0.0f), ih = fmaxf(rby - lty, 0.0f);
          const float inter = iw * ih;
          const float uni = (areaA + areaB) - inter;
          const float iou = inter / fmaxf(uni, 1e-6f);
          if (iou > 0.7f) { keep = 0; break; }
        }
        kp[p] = (u8)keep;
      }
    }
  }
  __syncthreads();

  // ---- writeback sorted outputs ----
  {
    const int p = tid;
    const u32 oi = (u32)key[p] & (BQ - 1);
    *reinterpret_cast<float4*>(boxes_g + (size_t)p * 4) = bx[oi];
    scores_g[p] = sc[oi];
    labels_g[p] = (float)lb[oi];
    keep_g[p]   = kp[p] ? 1.0f : 0.0f;
  }
  {
    const int p = tid + 1024;
    const u32 oi = (u32)key[p] & (BQ - 1);
    *reinterpret_cast<float4*>(boxes_g + (size_t)p * 4) = bx[oi];
    scores_g[p] = sc[oi];
    labels_g[p] = (float)lb[oi];
    keep_g[p]   = kp[p] ? 1.0f : 0.0f;
  }
}

extern "C" void kernel_launch(void* const* d_in, const int* in_sizes, int n_in,
                              void* d_out, int out_size, void* d_ws, size_t ws_size,
                              hipStream_t stream) {
  const float* logits = (const float*)d_in[0];
  const float* pboxes = (const float*)d_in[1];
  const int*   tsz    = (const int*)d_in[2];
  float* out = (float*)d_out;
  score_box_kernel<<<NB * BQ / 16, 256, 0, stream>>>(logits, pboxes, tsz, out);
  sort_nms_kernel<<<NB, 1024, 0, stream>>>(out);
}